// Round 3
// baseline (1518.041 us; speedup 1.0000x reference)
//
#include <hip/hip_runtime.h>
#include <math.h>

#define F_OUT     32
#define GRID_DIM  32
#define NUM_VOX   (GRID_DIM * GRID_DIM * GRID_DIM)

#define NPB   64             // nodes per payload bucket; bucket = dst >> 6
#define NBKT  1024           // bucket table size (Nn <= 65536)
#define SEB   1024           // edges per scatter block (2 per thread)
#define CAP   1344           // payload slots per bucket: mean 1024 + 10 sigma
#define SCS   132            // sC row stride (floats): 528 B, 16B-aligned
#define DEGS  125            // degree slot within sC row
#define CSTR  32             // cursor stride in uints: 128 B

// ---------- monotonic float<->uint encoding for atomicMax on signed floats ----
__device__ __forceinline__ unsigned int enc_f32(float f) {
    unsigned int u = __float_as_uint(f);
    return (u & 0x80000000u) ? ~u : (u | 0x80000000u);
}
__device__ __forceinline__ float dec_f32(unsigned int e) {
    return (e & 0x80000000u) ? __uint_as_float(e ^ 0x80000000u)
                             : __uint_as_float(~e);
}

// ---------- K1: bucket-scatter, batched loads --------------------------------
__global__ __launch_bounds__(512) void scatter_kernel(
    const int*   __restrict__ src,
    const int*   __restrict__ dst,
    const float* __restrict__ x,
    const float* __restrict__ pseudo,
    float4* __restrict__ payload,          // [NBKT * CAP]
    unsigned int* __restrict__ cursor,     // [NBKT * CSTR], pre-zeroed
    int E)
{
    __shared__ unsigned int sHist[NBKT];   // 4 KB
    __shared__ unsigned int sCur[NBKT];    // 4 KB

    const int t  = threadIdx.x;
    const int e0 = blockIdx.x * SEB;

    for (int i = t; i < NBKT; i += 512) sHist[i] = 0;
    __syncthreads();

    // pass A: all independent loads issued up-front, then dependent gathers.
    // validity is the INDEX RANGE (e < E) — dst==65535 is a legal value.
    const int eA = e0 + t, eB = e0 + 512 + t;
    const bool vA = eA < E, vB = eB < E;
    int   dA = 0, sA = 0, dB = 0, sB = 0;
    float pA0 = 0.f, pA1 = 0.f, pA2 = 0.f, pB0 = 0.f, pB1 = 0.f, pB2 = 0.f;
    if (vA) { dA = dst[eA]; sA = src[eA];
              pA0 = pseudo[3 * eA]; pA1 = pseudo[3 * eA + 1]; pA2 = pseudo[3 * eA + 2]; }
    if (vB) { dB = dst[eB]; sB = src[eB];
              pB0 = pseudo[3 * eB]; pB1 = pseudo[3 * eB + 1]; pB2 = pseudo[3 * eB + 2]; }
    float xA = vA ? x[sA] : 0.f;
    float xB = vB ? x[sB] : 0.f;

    unsigned short dlocA = 0, dlocB = 0;
    float4 payA, payB;
    if (vA) {
        unsigned int q2 = (unsigned int)(pA2 * 65535.0f + 0.5f) & 0xFFFFu;
        payA = make_float4(pA0, pA1, xA, __uint_as_float(q2 | ((unsigned int)(dA & 63) << 16)));
        dlocA = (unsigned short)dA;
        atomicAdd(&sHist[dA >> 6], 1u);
    }
    if (vB) {
        unsigned int q2 = (unsigned int)(pB2 * 65535.0f + 0.5f) & 0xFFFFu;
        payB = make_float4(pB0, pB1, xB, __uint_as_float(q2 | ((unsigned int)(dB & 63) << 16)));
        dlocB = (unsigned short)dB;
        atomicAdd(&sHist[dB >> 6], 1u);
    }
    __syncthreads();

    // reserve a contiguous range per touched bucket (padded global counters)
    for (int b = t; b < NBKT; b += 512) {
        unsigned int c = sHist[b];
        sCur[b] = c ? atomicAdd(&cursor[(size_t)b * CSTR], c) : 0u;
    }
    __syncthreads();

    // pass B: place payloads directly into the shared slabs
    if (vA) {
        unsigned int bkt  = (unsigned int)dlocA >> 6;
        unsigned int slot = atomicAdd(&sCur[bkt], 1u);
        if (slot < CAP) payload[(size_t)bkt * CAP + slot] = payA;
    }
    if (vB) {
        unsigned int bkt  = (unsigned int)dlocB >> 6;
        unsigned int slot = atomicAdd(&sCur[bkt], 1u);
        if (slot < CAP) payload[(size_t)bkt * CAP + slot] = payB;
    }
}

// ---------- per-edge accumulation: up to 9 scattered LDS atomics -------------
// Block owns a 32-node half of the bucket; edges of the other half are skipped.
__device__ __forceinline__ void process_edge(float4 r, float* sC, int half)
{
    unsigned int w = __float_as_uint(r.w);
    int rel6 = (int)((w >> 16) & 63u);
    if ((rel6 >> 5) != half) return;

    float xj = r.z;
    float p2 = (float)(w & 0xFFFFu) * (1.0f / 65535.0f);

    float v0 = r.x * 4.0f, v1 = r.y * 4.0f, v2 = p2 * 4.0f;
    float i0 = fminf(fmaxf(floorf(v0), 0.0f), 3.0f);
    float i1 = fminf(fmaxf(floorf(v1), 0.0f), 3.0f);
    float i2 = fminf(fmaxf(floorf(v2), 0.0f), 3.0f);
    float f0 = v0 - i0, f1 = v1 - i1, f2 = v2 - i2;
    float g0 = 1.0f - f0, g1 = 1.0f - f1, g2 = 1.0f - f2;
    int k = (int)i0 + 5 * (int)i1 + 25 * (int)i2;        // 0..93

    float w00 = g0 * g1, w10 = f0 * g1, w01 = g0 * f1, w11 = f0 * f1;
    float a2 = xj * g2, b2 = xj * f2;
    float* row = sC + (rel6 & 31) * SCS;
    atomicAdd(row + k +  0, w00 * a2);
    atomicAdd(row + k +  1, w10 * a2);
    atomicAdd(row + k +  5, w01 * a2);
    atomicAdd(row + k +  6, w11 * a2);
    atomicAdd(row + k + 25, w00 * b2);
    atomicAdd(row + k + 26, w10 * b2);
    atomicAdd(row + k + 30, w01 * b2);
    atomicAdd(row + k + 31, w11 * b2);
    atomicAdd(row + DEGS, 1.0f);                         // degree
}

// ---------- K2: owner half-bucket block — 32 nodes, 256 threads --------------
__global__ __launch_bounds__(256, 8) void owner_kernel(
    const float4* __restrict__ payload,
    const unsigned int* __restrict__ cursor,   // [NBKT*CSTR] bucket counts
    const float* __restrict__ W,        // [125,32]
    const float* __restrict__ x,        // [N,1]
    const float* __restrict__ W_root,   // [32]
    const float* __restrict__ bias,     // [32]
    const float* __restrict__ pos,      // [N,3]
    unsigned int* __restrict__ pooled,  // [NUM_VOX,32] encoded (aliases d_out)
    int Nn)
{
    __shared__ __align__(16) float sC[32 * SCS];   // 16896 B -> 8 blocks/CU

    const int t    = threadIdx.x;
    const int bp   = blockIdx.x;
    const int b    = bp >> 1;                 // payload bucket
    const int half = bp & 1;                  // 32-node half of the bucket

    // zero sC
    for (int i = t; i < 32 * SCS / 4; i += 256)
        *(float4*)&sC[i * 4] = make_float4(0.f, 0.f, 0.f, 0.f);
    __syncthreads();

    // edge phase: all 6 slab loads issued up-front (one latency exposure).
    // Sentinel payload self-predicates (rel-half mismatch) for i >= cnt.
    int cnt = (int)cursor[(size_t)b * CSTR];
    if (cnt > CAP) cnt = CAP;                 // unreachable
    const float4* slab = payload + (size_t)b * CAP;
    {
        const float4 sent = make_float4(0.f, 0.f, 0.f,
                                __uint_as_float((unsigned int)((half ^ 1) << 21)));
        float4 a0 = (t           < cnt) ? slab[t]           : sent;
        float4 a1 = (t +  256    < cnt) ? slab[t +  256]    : sent;
        float4 a2 = (t +  512    < cnt) ? slab[t +  512]    : sent;
        float4 a3 = (t +  768    < cnt) ? slab[t +  768]    : sent;
        float4 a4 = (t + 1024    < cnt) ? slab[t + 1024]    : sent;
        float4 a5 = (t + 1280    < cnt) ? slab[t + 1280]    : sent;
        process_edge(a0, sC, half);
        process_edge(a1, sC, half);
        process_edge(a2, sC, half);
        process_edge(a3, sC, half);
        process_edge(a4, sC, half);
        process_edge(a5, sC, half);
    }
    __syncthreads();

    // dense GEMM: [32 x 125] @ [125 x 32], manual double-buffer for ILP
    const int node = t & 31;
    const int cg   = t >> 5;                 // channel group 0..7
    const float* crow  = sC + node * SCS;
    const float* wbase = W + cg * 4;
    float4 acc = make_float4(0.f, 0.f, 0.f, 0.f);

    float4 rc  = *(const float4*)&crow[0];
    float4 w0c = *(const float4*)(wbase);
    float4 w1c = *(const float4*)(wbase + F_OUT);
    float4 w2c = *(const float4*)(wbase + 2 * F_OUT);
    float4 w3c = *(const float4*)(wbase + 3 * F_OUT);
    #pragma unroll
    for (int k4 = 0; k4 < 31; ++k4) {        // k = 0..123
        float4 rn, w0n, w1n, w2n, w3n;
        if (k4 < 30) {
            rn = *(const float4*)&crow[(k4 + 1) * 4];
            const float* wp = wbase + (size_t)(k4 + 1) * 4 * F_OUT;
            w0n = *(const float4*)(wp);
            w1n = *(const float4*)(wp + F_OUT);
            w2n = *(const float4*)(wp + 2 * F_OUT);
            w3n = *(const float4*)(wp + 3 * F_OUT);
        }
        acc.x += rc.x * w0c.x + rc.y * w1c.x + rc.z * w2c.x + rc.w * w3c.x;
        acc.y += rc.x * w0c.y + rc.y * w1c.y + rc.z * w2c.y + rc.w * w3c.y;
        acc.z += rc.x * w0c.z + rc.y * w1c.z + rc.z * w2c.z + rc.w * w3c.z;
        acc.w += rc.x * w0c.w + rc.y * w1c.w + rc.z * w2c.w + rc.w * w3c.w;
        if (k4 < 30) { rc = rn; w0c = w0n; w1c = w1n; w2c = w2n; w3c = w3n; }
    }
    {   // k = 124
        float r = crow[124];
        const float* wp = W + 124 * F_OUT + cg * 4;
        acc.x += r * wp[0]; acc.y += r * wp[1];
        acc.z += r * wp[2]; acc.w += r * wp[3];
    }
    float dg = fmaxf(crow[DEGS], 1.0f);
    int   n  = b * NPB + half * 32 + node;
    float xn = (n < Nn) ? x[n] : 0.0f;
    float4 wr = *(const float4*)(W_root + cg * 4);
    float4 bs = *(const float4*)(bias + cg * 4);
    __syncthreads();                          // all sC reads done

    // epilogue into sC slots 0..31 per node
    if (n < Nn) {
        float h;
        h = acc.x / dg + xn * wr.x + bs.x; h = h > 0.f ? h : expm1f(h); sC[node * SCS + cg * 4 + 0] = h;
        h = acc.y / dg + xn * wr.y + bs.y; h = h > 0.f ? h : expm1f(h); sC[node * SCS + cg * 4 + 1] = h;
        h = acc.z / dg + xn * wr.z + bs.z; h = h > 0.f ? h : expm1f(h); sC[node * SCS + cg * 4 + 2] = h;
        h = acc.w / dg + xn * wr.w + bs.w; h = h > 0.f ? h : expm1f(h); sC[node * SCS + cg * 4 + 3] = h;
    }
    __syncthreads();

    // voxel scatter-max, channel-coalesced (32 nodes x 32 channels)
    for (int item = t; item < 32 * F_OUT; item += 256) {
        int nr = item >> 5, o = item & 31;
        int nn = b * NPB + half * 32 + nr;
        if (nn >= Nn) break;
        int vx = min(max((int)floorf(pos[3 * nn + 0] * (float)GRID_DIM), 0), GRID_DIM - 1);
        int vy = min(max((int)floorf(pos[3 * nn + 1] * (float)GRID_DIM), 0), GRID_DIM - 1);
        int vz = min(max((int)floorf(pos[3 * nn + 2] * (float)GRID_DIM), 0), GRID_DIM - 1);
        int vidx = vx + GRID_DIM * vy + GRID_DIM * GRID_DIM * vz;
        atomicMax(&pooled[(size_t)vidx * F_OUT + o], enc_f32(sC[nr * SCS + o]));
    }
}

// ---------- K3: in-place decode on d_out, empty voxels -> 0 ------------------
__global__ __launch_bounds__(256) void finalize_kernel(
    const unsigned int* pooled,
    float* out, int M)
{
    int i = blockIdx.x * blockDim.x + threadIdx.x;
    if (i >= M) return;
    unsigned int u = pooled[i];
    out[i] = (u == 0u) ? 0.0f : dec_f32(u);
}

// ============================ launcher =======================================
extern "C" void kernel_launch(void* const* d_in, const int* in_sizes, int n_in,
                              void* d_out, int out_size, void* d_ws, size_t ws_size,
                              hipStream_t stream) {
    const float* x       = (const float*)d_in[0];
    const int*   ei      = (const int*)  d_in[1];
    const float* pseudo  = (const float*)d_in[2];
    const float* pos     = (const float*)d_in[3];
    const float* W       = (const float*)d_in[4];
    const float* W_root  = (const float*)d_in[5];
    const float* bias    = (const float*)d_in[6];

    const int E   = in_sizes[1] / 2;
    const int Nn  = in_sizes[0];                  // F_IN == 1, Nn <= 65536
    const int nSB = (E + SEB - 1) / SEB;          // scatter blocks (1024 here)
    const int nb  = 2 * ((Nn + NPB - 1) / NPB);   // owner half-bucket blocks (2048)

    // workspace: [payload NBKT*CAP*16 = 22.0 MB][cursor NBKT*CSTR*4 = 128 KB]
    float4*       payload = (float4*)d_ws;
    unsigned int* cursor  = (unsigned int*)((char*)d_ws + (size_t)NBKT * CAP * sizeof(float4));

    // pooled lives in d_out (encoded), decoded in place by finalize
    unsigned int* pooled = (unsigned int*)d_out;
    const int M = (out_size < NUM_VOX * F_OUT) ? out_size : NUM_VOX * F_OUT;

    hipMemsetAsync(cursor, 0, (size_t)NBKT * CSTR * sizeof(unsigned int), stream);
    hipMemsetAsync(d_out, 0, (size_t)M * sizeof(float), stream);

    scatter_kernel<<<nSB, 512, 0, stream>>>(ei, ei + E, x, pseudo, payload, cursor, E);
    owner_kernel<<<nb, 256, 0, stream>>>(payload, cursor, W, x, W_root, bias, pos,
                                         pooled, Nn);
    finalize_kernel<<<(M + 255) / 256, 256, 0, stream>>>(pooled, (float*)d_out, M);
}

// Round 4
// 1370.920 us; speedup vs baseline: 1.1073x; 1.1073x over previous
//
#include <hip/hip_runtime.h>
#include <math.h>

#define F_OUT     32
#define GRID_DIM  32
#define NUM_VOX   (GRID_DIM * GRID_DIM * GRID_DIM)

#define NPB   64             // nodes per payload bucket; bucket = dst >> 6
#define NBKT  1024           // bucket table size (Nn <= 65536)
#define SEB   1024           // edges per scatter block (2 per thread)
#define CAP   1344           // payload slots per bucket: mean 1024 + 10 sigma
#define SCS   132            // sC row stride (floats): 528 B, 16B-aligned
#define DEGS  125            // degree slot within sC row
#define CSTR  32             // cursor stride in uints: 128 B

// ---------- monotonic float<->uint encoding for atomicMax on signed floats ----
__device__ __forceinline__ unsigned int enc_f32(float f) {
    unsigned int u = __float_as_uint(f);
    return (u & 0x80000000u) ? ~u : (u | 0x80000000u);
}
__device__ __forceinline__ float dec_f32(unsigned int e) {
    return (e & 0x80000000u) ? __uint_as_float(e ^ 0x80000000u)
                             : __uint_as_float(~e);
}

// ---------- K1: bucket-scatter, batched loads --------------------------------
__global__ __launch_bounds__(512) void scatter_kernel(
    const int*   __restrict__ src,
    const int*   __restrict__ dst,
    const float* __restrict__ x,
    const float* __restrict__ pseudo,
    float4* __restrict__ payload,          // [NBKT * CAP]
    unsigned int* __restrict__ cursor,     // [NBKT * CSTR], pre-zeroed
    int E)
{
    __shared__ unsigned int sHist[NBKT];   // 4 KB
    __shared__ unsigned int sCur[NBKT];    // 4 KB

    const int t  = threadIdx.x;
    const int e0 = blockIdx.x * SEB;

    for (int i = t; i < NBKT; i += 512) sHist[i] = 0;
    __syncthreads();

    // pass A: all independent loads issued up-front, then dependent gathers.
    // validity is the INDEX RANGE (e < E) — dst==65535 is a legal value.
    const int eA = e0 + t, eB = e0 + 512 + t;
    const bool vA = eA < E, vB = eB < E;
    int   dA = 0, sA = 0, dB = 0, sB = 0;
    float pA0 = 0.f, pA1 = 0.f, pA2 = 0.f, pB0 = 0.f, pB1 = 0.f, pB2 = 0.f;
    if (vA) { dA = dst[eA]; sA = src[eA];
              pA0 = pseudo[3 * eA]; pA1 = pseudo[3 * eA + 1]; pA2 = pseudo[3 * eA + 2]; }
    if (vB) { dB = dst[eB]; sB = src[eB];
              pB0 = pseudo[3 * eB]; pB1 = pseudo[3 * eB + 1]; pB2 = pseudo[3 * eB + 2]; }
    float xA = vA ? x[sA] : 0.f;
    float xB = vB ? x[sB] : 0.f;

    unsigned short dlocA = 0, dlocB = 0;
    float4 payA, payB;
    if (vA) {
        unsigned int q2 = (unsigned int)(pA2 * 65535.0f + 0.5f) & 0xFFFFu;
        payA = make_float4(pA0, pA1, xA, __uint_as_float(q2 | ((unsigned int)(dA & 63) << 16)));
        dlocA = (unsigned short)dA;
        atomicAdd(&sHist[dA >> 6], 1u);
    }
    if (vB) {
        unsigned int q2 = (unsigned int)(pB2 * 65535.0f + 0.5f) & 0xFFFFu;
        payB = make_float4(pB0, pB1, xB, __uint_as_float(q2 | ((unsigned int)(dB & 63) << 16)));
        dlocB = (unsigned short)dB;
        atomicAdd(&sHist[dB >> 6], 1u);
    }
    __syncthreads();

    // reserve a contiguous range per touched bucket (padded global counters)
    for (int b = t; b < NBKT; b += 512) {
        unsigned int c = sHist[b];
        sCur[b] = c ? atomicAdd(&cursor[(size_t)b * CSTR], c) : 0u;
    }
    __syncthreads();

    // pass B: place payloads directly into the shared slabs
    if (vA) {
        unsigned int bkt  = (unsigned int)dlocA >> 6;
        unsigned int slot = atomicAdd(&sCur[bkt], 1u);
        if (slot < CAP) payload[(size_t)bkt * CAP + slot] = payA;
    }
    if (vB) {
        unsigned int bkt  = (unsigned int)dlocB >> 6;
        unsigned int slot = atomicAdd(&sCur[bkt], 1u);
        if (slot < CAP) payload[(size_t)bkt * CAP + slot] = payB;
    }
}

// ---------- per-edge accumulation: up to 9 scattered LDS atomics -------------
// Block owns a 32-node half of the bucket; edges of the other half are skipped.
__device__ __forceinline__ void process_edge(float4 r, float* sC, int half)
{
    unsigned int w = __float_as_uint(r.w);
    int rel6 = (int)((w >> 16) & 63u);
    if ((rel6 >> 5) != half) return;

    float xj = r.z;
    float p2 = (float)(w & 0xFFFFu) * (1.0f / 65535.0f);

    float v0 = r.x * 4.0f, v1 = r.y * 4.0f, v2 = p2 * 4.0f;
    float i0 = fminf(fmaxf(floorf(v0), 0.0f), 3.0f);
    float i1 = fminf(fmaxf(floorf(v1), 0.0f), 3.0f);
    float i2 = fminf(fmaxf(floorf(v2), 0.0f), 3.0f);
    float f0 = v0 - i0, f1 = v1 - i1, f2 = v2 - i2;
    float g0 = 1.0f - f0, g1 = 1.0f - f1, g2 = 1.0f - f2;
    int k = (int)i0 + 5 * (int)i1 + 25 * (int)i2;        // 0..93

    float w00 = g0 * g1, w10 = f0 * g1, w01 = g0 * f1, w11 = f0 * f1;
    float a2 = xj * g2, b2 = xj * f2;
    float* row = sC + (rel6 & 31) * SCS;
    atomicAdd(row + k +  0, w00 * a2);
    atomicAdd(row + k +  1, w10 * a2);
    atomicAdd(row + k +  5, w01 * a2);
    atomicAdd(row + k +  6, w11 * a2);
    atomicAdd(row + k + 25, w00 * b2);
    atomicAdd(row + k + 26, w10 * b2);
    atomicAdd(row + k + 30, w01 * b2);
    atomicAdd(row + k + 31, w11 * b2);
    atomicAdd(row + DEGS, 1.0f);                         // degree
}

// ---------- K2: owner half-bucket block — 32 nodes, 256 threads --------------
// __launch_bounds__(256, 4): 128-VGPR cap — the pipelined live set (~60 VGPR)
// must FIT; (256,8)'s 64-VGPR cap spilled to scratch (round-3: 3.7 GB traffic).
__global__ __launch_bounds__(256, 4) void owner_kernel(
    const float4* __restrict__ payload,
    const unsigned int* __restrict__ cursor,   // [NBKT*CSTR] bucket counts
    const float* __restrict__ W,        // [125,32]
    const float* __restrict__ x,        // [N,1]
    const float* __restrict__ W_root,   // [32]
    const float* __restrict__ bias,     // [32]
    const float* __restrict__ pos,      // [N,3]
    unsigned int* __restrict__ pooled,  // [NUM_VOX,32] encoded (aliases d_out)
    int Nn)
{
    __shared__ __align__(16) float sC[32 * SCS];   // 16896 B

    const int t    = threadIdx.x;
    const int bp   = blockIdx.x;
    const int b    = bp >> 1;                 // payload bucket
    const int half = bp & 1;                  // 32-node half of the bucket

    // zero sC
    for (int i = t; i < 32 * SCS / 4; i += 256)
        *(float4*)&sC[i * 4] = make_float4(0.f, 0.f, 0.f, 0.f);
    __syncthreads();

    // edge phase: all 6 slab loads issued up-front (one latency exposure).
    // Sentinel payload self-predicates (rel-half mismatch) for i >= cnt.
    int cnt = (int)cursor[(size_t)b * CSTR];
    if (cnt > CAP) cnt = CAP;                 // unreachable
    const float4* slab = payload + (size_t)b * CAP;
    {
        const float4 sent = make_float4(0.f, 0.f, 0.f,
                                __uint_as_float((unsigned int)((half ^ 1) << 21)));
        float4 a0 = (t           < cnt) ? slab[t]           : sent;
        float4 a1 = (t +  256    < cnt) ? slab[t +  256]    : sent;
        float4 a2 = (t +  512    < cnt) ? slab[t +  512]    : sent;
        float4 a3 = (t +  768    < cnt) ? slab[t +  768]    : sent;
        float4 a4 = (t + 1024    < cnt) ? slab[t + 1024]    : sent;
        float4 a5 = (t + 1280    < cnt) ? slab[t + 1280]    : sent;
        process_edge(a0, sC, half);
        process_edge(a1, sC, half);
        process_edge(a2, sC, half);
        process_edge(a3, sC, half);
        process_edge(a4, sC, half);
        process_edge(a5, sC, half);
    }
    __syncthreads();

    // dense GEMM: [32 x 125] @ [125 x 32], manual double-buffer for ILP
    const int node = t & 31;
    const int cg   = t >> 5;                 // channel group 0..7
    const float* crow  = sC + node * SCS;
    const float* wbase = W + cg * 4;
    float4 acc = make_float4(0.f, 0.f, 0.f, 0.f);

    float4 rc  = *(const float4*)&crow[0];
    float4 w0c = *(const float4*)(wbase);
    float4 w1c = *(const float4*)(wbase + F_OUT);
    float4 w2c = *(const float4*)(wbase + 2 * F_OUT);
    float4 w3c = *(const float4*)(wbase + 3 * F_OUT);
    #pragma unroll
    for (int k4 = 0; k4 < 31; ++k4) {        // k = 0..123
        float4 rn, w0n, w1n, w2n, w3n;
        if (k4 < 30) {
            rn = *(const float4*)&crow[(k4 + 1) * 4];
            const float* wp = wbase + (size_t)(k4 + 1) * 4 * F_OUT;
            w0n = *(const float4*)(wp);
            w1n = *(const float4*)(wp + F_OUT);
            w2n = *(const float4*)(wp + 2 * F_OUT);
            w3n = *(const float4*)(wp + 3 * F_OUT);
        }
        acc.x += rc.x * w0c.x + rc.y * w1c.x + rc.z * w2c.x + rc.w * w3c.x;
        acc.y += rc.x * w0c.y + rc.y * w1c.y + rc.z * w2c.y + rc.w * w3c.y;
        acc.z += rc.x * w0c.z + rc.y * w1c.z + rc.z * w2c.z + rc.w * w3c.z;
        acc.w += rc.x * w0c.w + rc.y * w1c.w + rc.z * w2c.w + rc.w * w3c.w;
        if (k4 < 30) { rc = rn; w0c = w0n; w1c = w1n; w2c = w2n; w3c = w3n; }
    }
    {   // k = 124
        float r = crow[124];
        const float* wp = W + 124 * F_OUT + cg * 4;
        acc.x += r * wp[0]; acc.y += r * wp[1];
        acc.z += r * wp[2]; acc.w += r * wp[3];
    }
    float dg = fmaxf(crow[DEGS], 1.0f);
    int   n  = b * NPB + half * 32 + node;
    float xn = (n < Nn) ? x[n] : 0.0f;
    float4 wr = *(const float4*)(W_root + cg * 4);
    float4 bs = *(const float4*)(bias + cg * 4);
    __syncthreads();                          // all sC reads done

    // epilogue into sC slots 0..31 per node
    if (n < Nn) {
        float h;
        h = acc.x / dg + xn * wr.x + bs.x; h = h > 0.f ? h : expm1f(h); sC[node * SCS + cg * 4 + 0] = h;
        h = acc.y / dg + xn * wr.y + bs.y; h = h > 0.f ? h : expm1f(h); sC[node * SCS + cg * 4 + 1] = h;
        h = acc.z / dg + xn * wr.z + bs.z; h = h > 0.f ? h : expm1f(h); sC[node * SCS + cg * 4 + 2] = h;
        h = acc.w / dg + xn * wr.w + bs.w; h = h > 0.f ? h : expm1f(h); sC[node * SCS + cg * 4 + 3] = h;
    }
    __syncthreads();

    // voxel scatter-max, channel-coalesced (32 nodes x 32 channels)
    for (int item = t; item < 32 * F_OUT; item += 256) {
        int nr = item >> 5, o = item & 31;
        int nn = b * NPB + half * 32 + nr;
        if (nn >= Nn) break;
        int vx = min(max((int)floorf(pos[3 * nn + 0] * (float)GRID_DIM), 0), GRID_DIM - 1);
        int vy = min(max((int)floorf(pos[3 * nn + 1] * (float)GRID_DIM), 0), GRID_DIM - 1);
        int vz = min(max((int)floorf(pos[3 * nn + 2] * (float)GRID_DIM), 0), GRID_DIM - 1);
        int vidx = vx + GRID_DIM * vy + GRID_DIM * GRID_DIM * vz;
        atomicMax(&pooled[(size_t)vidx * F_OUT + o], enc_f32(sC[nr * SCS + o]));
    }
}

// ---------- K3: in-place decode on d_out, empty voxels -> 0 ------------------
__global__ __launch_bounds__(256) void finalize_kernel(
    const unsigned int* pooled,
    float* out, int M)
{
    int i = blockIdx.x * blockDim.x + threadIdx.x;
    if (i >= M) return;
    unsigned int u = pooled[i];
    out[i] = (u == 0u) ? 0.0f : dec_f32(u);
}

// ============================ launcher =======================================
extern "C" void kernel_launch(void* const* d_in, const int* in_sizes, int n_in,
                              void* d_out, int out_size, void* d_ws, size_t ws_size,
                              hipStream_t stream) {
    const float* x       = (const float*)d_in[0];
    const int*   ei      = (const int*)  d_in[1];
    const float* pseudo  = (const float*)d_in[2];
    const float* pos     = (const float*)d_in[3];
    const float* W       = (const float*)d_in[4];
    const float* W_root  = (const float*)d_in[5];
    const float* bias    = (const float*)d_in[6];

    const int E   = in_sizes[1] / 2;
    const int Nn  = in_sizes[0];                  // F_IN == 1, Nn <= 65536
    const int nSB = (E + SEB - 1) / SEB;          // scatter blocks (1024 here)
    const int nb  = 2 * ((Nn + NPB - 1) / NPB);   // owner half-bucket blocks (2048)

    // workspace: [payload NBKT*CAP*16 = 22.0 MB][cursor NBKT*CSTR*4 = 128 KB]
    float4*       payload = (float4*)d_ws;
    unsigned int* cursor  = (unsigned int*)((char*)d_ws + (size_t)NBKT * CAP * sizeof(float4));

    // pooled lives in d_out (encoded), decoded in place by finalize
    unsigned int* pooled = (unsigned int*)d_out;
    const int M = (out_size < NUM_VOX * F_OUT) ? out_size : NUM_VOX * F_OUT;

    hipMemsetAsync(cursor, 0, (size_t)NBKT * CSTR * sizeof(unsigned int), stream);
    hipMemsetAsync(d_out, 0, (size_t)M * sizeof(float), stream);

    scatter_kernel<<<nSB, 512, 0, stream>>>(ei, ei + E, x, pseudo, payload, cursor, E);
    owner_kernel<<<nb, 256, 0, stream>>>(payload, cursor, W, x, W_root, bias, pos,
                                         pooled, Nn);
    finalize_kernel<<<(M + 255) / 256, 256, 0, stream>>>(pooled, (float*)d_out, M);
}

// Round 7
// 201.331 us; speedup vs baseline: 7.5400x; 6.8093x over previous
//
#include <hip/hip_runtime.h>
#include <math.h>

#define F_OUT     32
#define GRID_DIM  32
#define NUM_VOX   (GRID_DIM * GRID_DIM * GRID_DIM)

#define NPB   64             // nodes per payload bucket; bucket = dst >> 6
#define NBKT  1024           // bucket table size (Nn <= 65536)
#define SEB   2048           // edges per scatter block (4 per thread)
#define EPT   4              // edges per thread in scatter
#define CAP   1344           // payload slots per bucket: mean 1024 + 10 sigma
#define SCS   132            // sC row stride (floats): 528 B, 16B-aligned
#define DEGS  125            // degree slot within sC row
#define CSTR  32             // cursor stride in uints: 128 B

// native vector type for nontemporal builtins (HIP float4 is a class -> invalid)
typedef float vfloat4 __attribute__((ext_vector_type(4)));

__device__ __forceinline__ void nt_store_f4(float4 v, float4* p) {
    vfloat4 w; w.x = v.x; w.y = v.y; w.z = v.z; w.w = v.w;
    __builtin_nontemporal_store(w, (vfloat4*)p);
}
__device__ __forceinline__ float4 nt_load_f4(const float4* p) {
    vfloat4 w = __builtin_nontemporal_load((const vfloat4*)p);
    return make_float4(w.x, w.y, w.z, w.w);
}

// ---------- monotonic float<->uint encoding for atomicMax on signed floats ----
__device__ __forceinline__ unsigned int enc_f32(float f) {
    unsigned int u = __float_as_uint(f);
    return (u & 0x80000000u) ? ~u : (u | 0x80000000u);
}
__device__ __forceinline__ float dec_f32(unsigned int e) {
    return (e & 0x80000000u) ? __uint_as_float(e ^ 0x80000000u)
                             : __uint_as_float(~e);
}

// ---------- K1: bucket-scatter, nontemporal payload stores -------------------
// Payload stores are random 16B within 22MB: nt (no-allocate) avoids the
// write-allocate RFO+writeback amplification that made round-1/2's scatter
// ~90-110us. Order within a slab is irrelevant (accumulation is commutative).
__global__ __launch_bounds__(512) void scatter_kernel(
    const int*   __restrict__ src,
    const int*   __restrict__ dst,
    const float* __restrict__ x,
    const float* __restrict__ pseudo,
    float4* __restrict__ payload,          // [NBKT * CAP]
    unsigned int* __restrict__ cursor,     // [NBKT * CSTR], pre-zeroed
    int E)
{
    __shared__ unsigned int sHist[NBKT];   // 4 KB
    __shared__ unsigned int sCur[NBKT];    // 4 KB

    const int t  = threadIdx.x;
    const int e0 = blockIdx.x * SEB;

    for (int i = t; i < NBKT; i += 512) sHist[i] = 0;
    __syncthreads();

    // pass A: coalesced loads, payload built in registers, LDS histogram.
    // validity is the INDEX RANGE (e < E) — dst==65535 is a legal value.
    unsigned short dloc[EPT];
    float4 pay[EPT];
    #pragma unroll
    for (int i = 0; i < EPT; ++i) {
        int e = e0 + i * 512 + t;
        if (e < E) {
            int d = dst[e];
            int s = src[e];
            float p0 = pseudo[3 * e], p1 = pseudo[3 * e + 1], p2 = pseudo[3 * e + 2];
            float xj = x[s];
            unsigned int q2 = (unsigned int)(p2 * 65535.0f + 0.5f) & 0xFFFFu;
            unsigned int w  = q2 | ((unsigned int)(d & 63) << 16);
            dloc[i] = (unsigned short)d;
            pay[i]  = make_float4(p0, p1, xj, __uint_as_float(w));
            atomicAdd(&sHist[d >> 6], 1u);
        } else dloc[i] = 0;
    }
    __syncthreads();

    // reserve a contiguous range per touched bucket (padded global counters)
    for (int b = t; b < NBKT; b += 512) {
        unsigned int c = sHist[b];
        sCur[b] = c ? atomicAdd(&cursor[(size_t)b * CSTR], c) : 0u;
    }
    __syncthreads();

    // pass B: place payloads into the shared slabs, nontemporal
    #pragma unroll
    for (int i = 0; i < EPT; ++i) {
        int e = e0 + i * 512 + t;
        if (e < E) {
            unsigned int bkt  = (unsigned int)dloc[i] >> 6;
            unsigned int slot = atomicAdd(&sCur[bkt], 1u);
            if (slot < CAP)                       // unreachable at CAP = mean+10σ
                nt_store_f4(pay[i], &payload[(size_t)bkt * CAP + slot]);
        }
    }
}

// ---------- per-edge accumulation: up to 9 scattered LDS atomics -------------
// Block owns a 32-node half of the bucket; edges of the other half are skipped.
__device__ __forceinline__ void process_edge(float4 r, float* sC, int half)
{
    unsigned int w = __float_as_uint(r.w);
    int rel6 = (int)((w >> 16) & 63u);
    if ((rel6 >> 5) != half) return;

    float xj = r.z;
    float p2 = (float)(w & 0xFFFFu) * (1.0f / 65535.0f);

    float v0 = r.x * 4.0f, v1 = r.y * 4.0f, v2 = p2 * 4.0f;
    float i0 = fminf(fmaxf(floorf(v0), 0.0f), 3.0f);
    float i1 = fminf(fmaxf(floorf(v1), 0.0f), 3.0f);
    float i2 = fminf(fmaxf(floorf(v2), 0.0f), 3.0f);
    float f0 = v0 - i0, f1 = v1 - i1, f2 = v2 - i2;
    float g0 = 1.0f - f0, g1 = 1.0f - f1, g2 = 1.0f - f2;
    int k = (int)i0 + 5 * (int)i1 + 25 * (int)i2;        // 0..93

    float w00 = g0 * g1, w10 = f0 * g1, w01 = g0 * f1, w11 = f0 * f1;
    float a2 = xj * g2, b2 = xj * f2;
    float* row = sC + (rel6 & 31) * SCS;
    atomicAdd(row + k +  0, w00 * a2);
    atomicAdd(row + k +  1, w10 * a2);
    atomicAdd(row + k +  5, w01 * a2);
    atomicAdd(row + k +  6, w11 * a2);
    atomicAdd(row + k + 25, w00 * b2);
    atomicAdd(row + k + 26, w10 * b2);
    atomicAdd(row + k + 30, w01 * b2);
    atomicAdd(row + k + 31, w11 * b2);
    atomicAdd(row + DEGS, 1.0f);                         // degree
}

// ---------- K2: owner half-bucket block — 32 nodes, 256 threads --------------
// Round-2 structure (known-good, VGPR~36): simple #pragma unroll 8 GEMM.
// Only additions: 6 up-front sentinel-predicated nt slab loads.
__global__ __launch_bounds__(256) void owner_kernel(
    const float4* __restrict__ payload,
    const unsigned int* __restrict__ cursor,   // [NBKT*CSTR] bucket counts
    const float* __restrict__ W,        // [125,32]
    const float* __restrict__ x,        // [N,1]
    const float* __restrict__ W_root,   // [32]
    const float* __restrict__ bias,     // [32]
    const float* __restrict__ pos,      // [N,3]
    unsigned int* __restrict__ pooled,  // [NUM_VOX,32] encoded (aliases d_out)
    int Nn)
{
    __shared__ __align__(16) float sC[32 * SCS];   // 16896 B

    const int t    = threadIdx.x;
    const int bp   = blockIdx.x;
    const int b    = bp >> 1;                 // payload bucket
    const int half = bp & 1;                  // 32-node half of the bucket

    // zero sC
    for (int i = t; i < 32 * SCS / 4; i += 256)
        *(float4*)&sC[i * 4] = make_float4(0.f, 0.f, 0.f, 0.f);
    __syncthreads();

    // edge phase: all 6 slab loads issued up-front (one latency exposure).
    // Sentinel payload self-predicates (rel-half mismatch) for i >= cnt.
    int cnt = (int)cursor[(size_t)b * CSTR];
    if (cnt > CAP) cnt = CAP;                 // unreachable
    const float4* slab = payload + (size_t)b * CAP;
    {
        const float4 sent = make_float4(0.f, 0.f, 0.f,
                                __uint_as_float((unsigned int)((half ^ 1) << 21)));
        float4 a0 = (t        < cnt) ? nt_load_f4(&slab[t])        : sent;
        float4 a1 = (t +  256 < cnt) ? nt_load_f4(&slab[t +  256]) : sent;
        float4 a2 = (t +  512 < cnt) ? nt_load_f4(&slab[t +  512]) : sent;
        float4 a3 = (t +  768 < cnt) ? nt_load_f4(&slab[t +  768]) : sent;
        float4 a4 = (t + 1024 < cnt) ? nt_load_f4(&slab[t + 1024]) : sent;
        float4 a5 = (t + 1280 < cnt) ? nt_load_f4(&slab[t + 1280]) : sent;
        process_edge(a0, sC, half);
        process_edge(a1, sC, half);
        process_edge(a2, sC, half);
        process_edge(a3, sC, half);
        process_edge(a4, sC, half);
        process_edge(a5, sC, half);
    }
    __syncthreads();

    // dense GEMM: [32 x 125] @ [125 x 32], 4 channels/thread, b128 LDS reads
    const int node = t & 31;
    const int cg   = t >> 5;                 // channel group 0..7
    const float* crow = sC + node * SCS;
    float4 acc = make_float4(0.f, 0.f, 0.f, 0.f);
    #pragma unroll 8
    for (int k4 = 0; k4 < 31; ++k4) {        // k = 0..123
        float4 r = *(const float4*)&crow[k4 * 4];
        const float* wp = W + (k4 * 4) * F_OUT + cg * 4;
        float4 w0 = *(const float4*)(wp);
        float4 w1 = *(const float4*)(wp + F_OUT);
        float4 w2 = *(const float4*)(wp + 2 * F_OUT);
        float4 w3 = *(const float4*)(wp + 3 * F_OUT);
        acc.x += r.x * w0.x + r.y * w1.x + r.z * w2.x + r.w * w3.x;
        acc.y += r.x * w0.y + r.y * w1.y + r.z * w2.y + r.w * w3.y;
        acc.z += r.x * w0.z + r.y * w1.z + r.z * w2.z + r.w * w3.z;
        acc.w += r.x * w0.w + r.y * w1.w + r.z * w2.w + r.w * w3.w;
    }
    {   // k = 124
        float r = crow[124];
        const float* wp = W + 124 * F_OUT + cg * 4;
        acc.x += r * wp[0]; acc.y += r * wp[1];
        acc.z += r * wp[2]; acc.w += r * wp[3];
    }
    float dg = fmaxf(crow[DEGS], 1.0f);
    int   n  = b * NPB + half * 32 + node;
    float xn = (n < Nn) ? x[n] : 0.0f;
    float4 wr = *(const float4*)(W_root + cg * 4);
    float4 bs = *(const float4*)(bias + cg * 4);
    __syncthreads();                          // all sC reads done

    // epilogue into sC slots 0..31 per node
    if (n < Nn) {
        float h;
        h = acc.x / dg + xn * wr.x + bs.x; h = h > 0.f ? h : expm1f(h); sC[node * SCS + cg * 4 + 0] = h;
        h = acc.y / dg + xn * wr.y + bs.y; h = h > 0.f ? h : expm1f(h); sC[node * SCS + cg * 4 + 1] = h;
        h = acc.z / dg + xn * wr.z + bs.z; h = h > 0.f ? h : expm1f(h); sC[node * SCS + cg * 4 + 2] = h;
        h = acc.w / dg + xn * wr.w + bs.w; h = h > 0.f ? h : expm1f(h); sC[node * SCS + cg * 4 + 3] = h;
    }
    __syncthreads();

    // voxel scatter-max, channel-coalesced (32 nodes x 32 channels)
    for (int item = t; item < 32 * F_OUT; item += 256) {
        int nr = item >> 5, o = item & 31;
        int nn = b * NPB + half * 32 + nr;
        if (nn >= Nn) break;
        int vx = min(max((int)floorf(pos[3 * nn + 0] * (float)GRID_DIM), 0), GRID_DIM - 1);
        int vy = min(max((int)floorf(pos[3 * nn + 1] * (float)GRID_DIM), 0), GRID_DIM - 1);
        int vz = min(max((int)floorf(pos[3 * nn + 2] * (float)GRID_DIM), 0), GRID_DIM - 1);
        int vidx = vx + GRID_DIM * vy + GRID_DIM * GRID_DIM * vz;
        atomicMax(&pooled[(size_t)vidx * F_OUT + o], enc_f32(sC[nr * SCS + o]));
    }
}

// ---------- K3: in-place decode on d_out, empty voxels -> 0 ------------------
__global__ __launch_bounds__(256) void finalize_kernel(
    const unsigned int* pooled,
    float* out, int M)
{
    int i = blockIdx.x * blockDim.x + threadIdx.x;
    if (i >= M) return;
    unsigned int u = pooled[i];
    out[i] = (u == 0u) ? 0.0f : dec_f32(u);
}

// ============================ launcher =======================================
extern "C" void kernel_launch(void* const* d_in, const int* in_sizes, int n_in,
                              void* d_out, int out_size, void* d_ws, size_t ws_size,
                              hipStream_t stream) {
    const float* x       = (const float*)d_in[0];
    const int*   ei      = (const int*)  d_in[1];
    const float* pseudo  = (const float*)d_in[2];
    const float* pos     = (const float*)d_in[3];
    const float* W       = (const float*)d_in[4];
    const float* W_root  = (const float*)d_in[5];
    const float* bias    = (const float*)d_in[6];

    const int E   = in_sizes[1] / 2;
    const int Nn  = in_sizes[0];                  // F_IN == 1, Nn <= 65536
    const int nSB = (E + SEB - 1) / SEB;          // scatter blocks (512 here)
    const int nb  = 2 * ((Nn + NPB - 1) / NPB);   // owner half-bucket blocks (2048)

    // workspace: [payload NBKT*CAP*16 = 22.0 MB][cursor NBKT*CSTR*4 = 128 KB]
    float4*       payload = (float4*)d_ws;
    unsigned int* cursor  = (unsigned int*)((char*)d_ws + (size_t)NBKT * CAP * sizeof(float4));

    // pooled lives in d_out (encoded), decoded in place by finalize
    unsigned int* pooled = (unsigned int*)d_out;
    const int M = (out_size < NUM_VOX * F_OUT) ? out_size : NUM_VOX * F_OUT;

    hipMemsetAsync(cursor, 0, (size_t)NBKT * CSTR * sizeof(unsigned int), stream);
    hipMemsetAsync(d_out, 0, (size_t)M * sizeof(float), stream);

    scatter_kernel<<<nSB, 512, 0, stream>>>(ei, ei + E, x, pseudo, payload, cursor, E);
    owner_kernel<<<nb, 256, 0, stream>>>(payload, cursor, W, x, W_root, bias, pos,
                                         pooled, Nn);
    finalize_kernel<<<(M + 255) / 256, 256, 0, stream>>>(pooled, (float*)d_out, M);
}

// Round 8
// 179.408 us; speedup vs baseline: 8.4614x; 1.1222x over previous
//
#include <hip/hip_runtime.h>
#include <math.h>

#define F_OUT     32
#define GRID_DIM  32
#define NUM_VOX   (GRID_DIM * GRID_DIM * GRID_DIM)

#define NGRP  256            // node groups; g = dst >> 8 (256 nodes/group)
#define GNPB  256            // nodes per group
#define HNPB  128            // nodes per owner block (half group)
#define SEB   2048           // edges per scatter block (4 per thread, 512 thr)
#define EPT   4
#define BCAP  4480           // bin capacity: mean 3906 + ~9 sigma
#define SCS   132            // sC row stride (floats): 528 B, 16B-aligned
#define DEGS  125            // degree slot within sC row
#define CSTR  32             // cursor stride in uints: 128 B

// ---------- monotonic float<->uint encoding for atomicMax on signed floats ----
__device__ __forceinline__ unsigned int enc_f32(float f) {
    unsigned int u = __float_as_uint(f);
    return (u & 0x80000000u) ? ~u : (u | 0x80000000u);
}
__device__ __forceinline__ float dec_f32(unsigned int e) {
    return (e & 0x80000000u) ? __uint_as_float(e ^ 0x80000000u)
                             : __uint_as_float(~e);
}

// ---------- K1: coarse-group scatter with LDS-staged COALESCED streamout -----
// Random 16B global stores were the wall (rounds 1-7). Staging 2048 payloads
// in LDS sorted by 256 coarse groups makes streamout runs ~8 slots = 128B
// contiguous bursts. Shared global bins (dense) replace private slabs+off_tab.
__global__ __launch_bounds__(512) void scatter_kernel(
    const int*   __restrict__ src,
    const int*   __restrict__ dst,
    const float* __restrict__ x,
    const float* __restrict__ pseudo,
    float4* __restrict__ payload,          // [NGRP * BCAP]
    unsigned int* __restrict__ cursor,     // [NGRP * CSTR], pre-zeroed
    int E)
{
    __shared__ unsigned int sHist[NGRP];    // counts -> placement cursor (1 KB)
    __shared__ unsigned int sStart[NGRP];   // block-local exclusive starts
    __shared__ unsigned int sGBase[NGRP];   // global bin base per group
    __shared__ unsigned int sTotal;
    __shared__ unsigned short sGid[SEB];    // group id per staged slot (4 KB)
    __shared__ __align__(16) float4 sPay[SEB];   // staged payload (32 KB)

    const int t  = threadIdx.x;
    const int e0 = blockIdx.x * SEB;

    if (t < NGRP) sHist[t] = 0;
    __syncthreads();

    // pass A: coalesced loads, payload in registers, 256-entry histogram.
    // validity is the INDEX RANGE (e < E) — any dst value is legal data.
    unsigned short dloc[EPT];
    float4 pay[EPT];
    bool   val[EPT];
    #pragma unroll
    for (int i = 0; i < EPT; ++i) {
        int e = e0 + i * 512 + t;
        val[i] = (e < E);
        if (val[i]) {
            int d = dst[e];
            int s = src[e];
            float p0 = pseudo[3 * e], p1 = pseudo[3 * e + 1], p2 = pseudo[3 * e + 2];
            float xj = x[s];
            unsigned int q2 = (unsigned int)(p2 * 65535.0f + 0.5f) & 0xFFFFu;
            pay[i]  = make_float4(p0, p1, xj,
                        __uint_as_float(q2 | ((unsigned int)(d & 255) << 16)));
            dloc[i] = (unsigned short)d;
            atomicAdd(&sHist[(d >> 8) & 255], 1u);
        } else dloc[i] = 0;
    }
    __syncthreads();

    // exclusive scan of 256 counts: single wave, shfl-based (no barriers inside)
    if (t < 64) {
        unsigned int c0 = sHist[4*t], c1 = sHist[4*t+1], c2 = sHist[4*t+2], c3 = sHist[4*t+3];
        unsigned int loc = c0 + c1 + c2 + c3;
        unsigned int incl = loc;
        #pragma unroll
        for (int d = 1; d < 64; d <<= 1) {
            unsigned int v = __shfl_up(incl, d, 64);
            if (t >= d) incl += v;
        }
        unsigned int excl = incl - loc;
        sStart[4*t]   = excl;
        sStart[4*t+1] = excl + c0;
        sStart[4*t+2] = excl + c0 + c1;
        sStart[4*t+3] = excl + c0 + c1 + c2;
        if (t == 63) sTotal = incl;
    }
    __syncthreads();

    // reserve global bin ranges; repurpose sHist as placement cursor
    if (t < NGRP) {
        unsigned int c = sHist[t];
        sGBase[t] = c ? atomicAdd(&cursor[(size_t)t * CSTR], c) : 0u;
        sHist[t]  = sStart[t];
    }
    __syncthreads();

    // place payloads into LDS, sorted by group
    #pragma unroll
    for (int i = 0; i < EPT; ++i) {
        if (val[i]) {
            unsigned int g = ((unsigned int)dloc[i] >> 8) & 255u;
            unsigned int slot = atomicAdd(&sHist[g], 1u);
            sPay[slot] = pay[i];
            sGid[slot] = (unsigned short)g;
        }
    }
    __syncthreads();

    // coalesced streamout: consecutive staged slots -> consecutive bin slots
    const unsigned int total = sTotal;
    for (unsigned int i = t; i < total; i += 512) {
        unsigned int g   = sGid[i];
        unsigned int idx = sGBase[g] + (i - sStart[g]);
        if (idx < BCAP)                      // unreachable at BCAP = mean+9σ
            payload[(size_t)g * BCAP + idx] = sPay[i];
    }
}

// ---------- per-edge accumulation: up to 9 scattered LDS atomics -------------
// Owner block owns a 128-node half of the group; other-half edges are skipped.
__device__ __forceinline__ void process_edge(float4 r, float* sC, int half)
{
    unsigned int w = __float_as_uint(r.w);
    int rel8 = (int)((w >> 16) & 255u);
    if ((rel8 >> 7) != half) return;

    float xj = r.z;
    float p2 = (float)(w & 0xFFFFu) * (1.0f / 65535.0f);

    float v0 = r.x * 4.0f, v1 = r.y * 4.0f, v2 = p2 * 4.0f;
    float i0 = fminf(fmaxf(floorf(v0), 0.0f), 3.0f);
    float i1 = fminf(fmaxf(floorf(v1), 0.0f), 3.0f);
    float i2 = fminf(fmaxf(floorf(v2), 0.0f), 3.0f);
    float f0 = v0 - i0, f1 = v1 - i1, f2 = v2 - i2;
    float g0 = 1.0f - f0, g1 = 1.0f - f1, g2 = 1.0f - f2;
    int k = (int)i0 + 5 * (int)i1 + 25 * (int)i2;        // 0..93

    float w00 = g0 * g1, w10 = f0 * g1, w01 = g0 * f1, w11 = f0 * f1;
    float a2 = xj * g2, b2 = xj * f2;
    float* row = sC + (rel8 & 127) * SCS;
    atomicAdd(row + k +  0, w00 * a2);
    atomicAdd(row + k +  1, w10 * a2);
    atomicAdd(row + k +  5, w01 * a2);
    atomicAdd(row + k +  6, w11 * a2);
    atomicAdd(row + k + 25, w00 * b2);
    atomicAdd(row + k + 26, w10 * b2);
    atomicAdd(row + k + 30, w01 * b2);
    atomicAdd(row + k + 31, w11 * b2);
    atomicAdd(row + DEGS, 1.0f);                         // degree
}

// ---------- K2: owner half-group block — 128 nodes, 256 threads --------------
// ~17 prefetched edge iterations per block: enough depth to pipeline loads
// against LDS atomics (round-7's one-shot blocks exposed all latency once).
__global__ __launch_bounds__(256) void owner_kernel(
    const float4* __restrict__ payload,
    const unsigned int* __restrict__ cursor,   // [NGRP*CSTR] bin counts
    const float* __restrict__ W,        // [125,32]
    const float* __restrict__ x,        // [N,1]
    const float* __restrict__ W_root,   // [32]
    const float* __restrict__ bias,     // [32]
    const float* __restrict__ pos,      // [N,3]
    unsigned int* __restrict__ pooled,  // [NUM_VOX,32] encoded (aliases d_out)
    int Nn)
{
    __shared__ __align__(16) float sC[HNPB * SCS];   // 67584 B -> 2 blocks/CU

    const int t    = threadIdx.x;
    const int g    = blockIdx.x >> 1;
    const int half = blockIdx.x & 1;

    // zero sC
    for (int i = t; i < HNPB * SCS / 4; i += 256)
        ((float4*)sC)[i] = make_float4(0.f, 0.f, 0.f, 0.f);

    int cnt = (int)cursor[(size_t)g * CSTR];
    if (cnt > BCAP) cnt = BCAP;                 // unreachable
    const float4* slab = payload + (size_t)g * BCAP;
    __syncthreads();

    // edge phase: contiguous dense bin stream, 1-deep prefetch
    {
        int i = t;
        if (i < cnt) {
            float4 r = slab[i];
            for (i += 256; i < cnt; i += 256) {
                float4 rn = slab[i];            // overlap load with atomics
                process_edge(r, sC, half);
                r = rn;
            }
            process_edge(r, sC, half);
        }
    }
    __syncthreads();

    // GEMM + epilogue, 4 tiles of 32 nodes; r2's known-good unroll-8 body
    const int nl = t & 31;                   // node within tile
    const int cg = t >> 5;                   // channel group 0..7
    const float4 wr = *(const float4*)(W_root + cg * 4);
    const float4 bs = *(const float4*)(bias + cg * 4);

    #pragma unroll
    for (int tile = 0; tile < 4; ++tile) {
        const int node = tile * 32 + nl;
        const float* crow = sC + node * SCS;
        float4 acc = make_float4(0.f, 0.f, 0.f, 0.f);
        #pragma unroll 8
        for (int k4 = 0; k4 < 31; ++k4) {    // k = 0..123
            float4 r = *(const float4*)&crow[k4 * 4];
            const float* wp = W + (k4 * 4) * F_OUT + cg * 4;
            float4 w0 = *(const float4*)(wp);
            float4 w1 = *(const float4*)(wp + F_OUT);
            float4 w2 = *(const float4*)(wp + 2 * F_OUT);
            float4 w3 = *(const float4*)(wp + 3 * F_OUT);
            acc.x += r.x * w0.x + r.y * w1.x + r.z * w2.x + r.w * w3.x;
            acc.y += r.x * w0.y + r.y * w1.y + r.z * w2.y + r.w * w3.y;
            acc.z += r.x * w0.z + r.y * w1.z + r.z * w2.z + r.w * w3.z;
            acc.w += r.x * w0.w + r.y * w1.w + r.z * w2.w + r.w * w3.w;
        }
        {   // k = 124
            float r = crow[124];
            const float* wp = W + 124 * F_OUT + cg * 4;
            acc.x += r * wp[0]; acc.y += r * wp[1];
            acc.z += r * wp[2]; acc.w += r * wp[3];
        }
        float dg = fmaxf(crow[DEGS], 1.0f);
        int   n  = g * GNPB + half * HNPB + node;
        float xn = (n < Nn) ? x[n] : 0.0f;
        __syncthreads();                     // tile's sC reads done block-wide
        if (n < Nn) {                        // epilogue into rows of THIS tile only
            float h;
            h = acc.x / dg + xn * wr.x + bs.x; h = h > 0.f ? h : expm1f(h); sC[node * SCS + cg * 4 + 0] = h;
            h = acc.y / dg + xn * wr.y + bs.y; h = h > 0.f ? h : expm1f(h); sC[node * SCS + cg * 4 + 1] = h;
            h = acc.z / dg + xn * wr.z + bs.z; h = h > 0.f ? h : expm1f(h); sC[node * SCS + cg * 4 + 2] = h;
            h = acc.w / dg + xn * wr.w + bs.w; h = h > 0.f ? h : expm1f(h); sC[node * SCS + cg * 4 + 3] = h;
        }
    }
    __syncthreads();

    // voxel scatter-max, channel-coalesced (128 nodes x 32 channels)
    for (int item = t; item < HNPB * F_OUT; item += 256) {
        int nr = item >> 5, o = item & 31;
        int nn = g * GNPB + half * HNPB + nr;
        if (nn >= Nn) continue;
        int vx = min(max((int)floorf(pos[3 * nn + 0] * (float)GRID_DIM), 0), GRID_DIM - 1);
        int vy = min(max((int)floorf(pos[3 * nn + 1] * (float)GRID_DIM), 0), GRID_DIM - 1);
        int vz = min(max((int)floorf(pos[3 * nn + 2] * (float)GRID_DIM), 0), GRID_DIM - 1);
        int vidx = vx + GRID_DIM * vy + GRID_DIM * GRID_DIM * vz;
        atomicMax(&pooled[(size_t)vidx * F_OUT + o], enc_f32(sC[nr * SCS + o]));
    }
}

// ---------- K3: in-place decode on d_out, empty voxels -> 0 ------------------
__global__ __launch_bounds__(256) void finalize_kernel(
    const unsigned int* pooled,
    float* out, int M)
{
    int i = blockIdx.x * blockDim.x + threadIdx.x;
    if (i >= M) return;
    unsigned int u = pooled[i];
    out[i] = (u == 0u) ? 0.0f : dec_f32(u);
}

// ============================ launcher =======================================
extern "C" void kernel_launch(void* const* d_in, const int* in_sizes, int n_in,
                              void* d_out, int out_size, void* d_ws, size_t ws_size,
                              hipStream_t stream) {
    const float* x       = (const float*)d_in[0];
    const int*   ei      = (const int*)  d_in[1];
    const float* pseudo  = (const float*)d_in[2];
    const float* pos     = (const float*)d_in[3];
    const float* W       = (const float*)d_in[4];
    const float* W_root  = (const float*)d_in[5];
    const float* bias    = (const float*)d_in[6];

    const int E    = in_sizes[1] / 2;
    const int Nn   = in_sizes[0];                 // F_IN == 1, Nn <= 65536
    const int nSB  = (E + SEB - 1) / SEB;         // scatter blocks (512 here)
    const int nb   = 2 * ((Nn + GNPB - 1) / GNPB);// owner half-group blocks (512)

    // workspace: [payload NGRP*BCAP*16 = 18.35 MB][cursor NGRP*CSTR*4 = 32 KB]
    float4*       payload = (float4*)d_ws;
    unsigned int* cursor  = (unsigned int*)((char*)d_ws + (size_t)NGRP * BCAP * sizeof(float4));

    // pooled lives in d_out (encoded), decoded in place by finalize
    unsigned int* pooled = (unsigned int*)d_out;
    const int M = (out_size < NUM_VOX * F_OUT) ? out_size : NUM_VOX * F_OUT;

    hipMemsetAsync(cursor, 0, (size_t)NGRP * CSTR * sizeof(unsigned int), stream);
    hipMemsetAsync(d_out, 0, (size_t)M * sizeof(float), stream);

    scatter_kernel<<<nSB, 512, 0, stream>>>(ei, ei + E, x, pseudo, payload, cursor, E);
    owner_kernel<<<nb, 256, 0, stream>>>(payload, cursor, W, x, W_root, bias, pos,
                                         pooled, Nn);
    finalize_kernel<<<(M + 255) / 256, 256, 0, stream>>>(pooled, (float*)d_out, M);
}